// Round 2
// baseline (359.091 us; speedup 1.0000x reference)
//
#include <hip/hip_runtime.h>

// UIGen_63058709840320: I=32000, L=2048, D=256.
// Collapse: out = (weighted[L-2] + weighted[L-1]) @ D2; upstream chain only
// needs rows L-2, L-1 of posEmbed/dense1. pool1/pool2 at rows L-2/L-1 are
// elementwise: row L-2 -> (a+b)/2047, row L-1 -> b/2048.
//
// 4 graph nodes, no memsets, no global atomics:
//   k_rows  : 250 blocks, DE gemv partials -> ws                (reads 33 MB)
//   k_dense1: 16 blocks, reduce partials + PE, matvec D1 -> pd1 partials
//   k_att   : 16 blocks, reduce pd1, matvec Att -> patt partials
//   k_out   : 250 blocks, reduce pd1/patt -> s[256], s @ D2 -> out (reads 33 MB)
namespace {
constexpr int LL = 2048;
constexpr int II = 32000;
constexpr int DD = 256;
constexpr int NB = 250;          // k_rows blocks

// ---- Kernel 1: partial[b][0..255] += x[L-2] @ DE, [256..511] x[L-1] @ DE ----
__global__ __launch_bounds__(256) void k_rows(const float* __restrict__ x,
                                              const float* __restrict__ DE,
                                              float* __restrict__ partial) {
  const int lane = threadIdx.x & 63;   // float4 group within D (64*4 = 256)
  const int sub  = threadIdx.x >> 6;   // 0..3, i interleave
  const float4* __restrict__ DE4 = reinterpret_cast<const float4*>(DE);
  const float* __restrict__ x0 = x + (size_t)(LL - 2) * II;
  const float* __restrict__ x1 = x + (size_t)(LL - 1) * II;
  const int i0 = blockIdx.x * 128;
  float4 a0 = {0.f, 0.f, 0.f, 0.f};
  float4 a1 = {0.f, 0.f, 0.f, 0.f};
#pragma unroll 8
  for (int ii = 0; ii < 32; ++ii) {
    const int i = i0 + sub + 4 * ii;
    const float4 de = DE4[(size_t)i * (DD / 4) + lane];
    const float s0 = x0[i];
    const float s1 = x1[i];
    a0.x = fmaf(s0, de.x, a0.x); a0.y = fmaf(s0, de.y, a0.y);
    a0.z = fmaf(s0, de.z, a0.z); a0.w = fmaf(s0, de.w, a0.w);
    a1.x = fmaf(s1, de.x, a1.x); a1.y = fmaf(s1, de.y, a1.y);
    a1.z = fmaf(s1, de.z, a1.z); a1.w = fmaf(s1, de.w, a1.w);
  }
  __shared__ float red[8][DD];  // [sub*2 + row][d]
  {
    float* r0 = &red[sub * 2 + 0][lane * 4];
    r0[0] = a0.x; r0[1] = a0.y; r0[2] = a0.z; r0[3] = a0.w;
    float* r1 = &red[sub * 2 + 1][lane * 4];
    r1[0] = a1.x; r1[1] = a1.y; r1[2] = a1.z; r1[3] = a1.w;
  }
  __syncthreads();
  const int d = threadIdx.x;
  const float s0 = red[0][d] + red[2][d] + red[4][d] + red[6][d];
  const float s1 = red[1][d] + red[3][d] + red[5][d] + red[7][d];
  float* p = partial + (size_t)blockIdx.x * 512;
  p[d] = s0;
  p[DD + d] = s1;
}

// ---- Kernel 2: dense1 rows L-2/L-1, k-chunked; reduces k_rows partials ----
__global__ __launch_bounds__(256) void k_dense1(const float* __restrict__ partial,
                                                const float* __restrict__ PE,
                                                const float* __restrict__ D1,
                                                float* __restrict__ pd1) {
  const int c = blockIdx.x;            // 0..15  (k-chunk of 32)
  const int t = threadIdx.x;
  const int jbase = (c & 7) * 32;      // j-range this chunk touches
  __shared__ float red2[4][64];
  __shared__ float A[32], B[32], va[32], vb[32];
  {
    const int r = t >> 6;              // 0..3 partial-subset
    const int idx = t & 63;            // row*32 + jj
    const int row = idx >> 5;
    const int col = row * DD + jbase + (idx & 31);
    float s = 0.f;
    for (int b = r; b < NB; b += 4) s += partial[(size_t)b * 512 + col];
    red2[r][idx] = s;
  }
  __syncthreads();
  if (t < 64) {
    const int row = t >> 5;
    const int jj = t & 31;
    const float acc = red2[0][t] + red2[1][t] + red2[2][t] + red2[3][t] +
                      PE[(size_t)(LL - 2 + row) * DD + jbase + jj];
    if (row == 0) A[jj] = acc; else B[jj] = acc;
  }
  __syncthreads();
  if (t < 32) {
    const float a = A[t], b = B[t];
    if (c < 8) { va[t] = a; vb[t] = b; }
    else {
      va[t] = (a + b) * (1.0f / (float)(LL - 1));
      vb[t] = b * (1.0f / (float)LL);
    }
  }
  __syncthreads();
  const int k0 = c * 32;
  float sa = 0.f, sb = 0.f;
#pragma unroll 8
  for (int kk = 0; kk < 32; ++kk) {
    const float w = D1[(size_t)(k0 + kk) * DD + t];
    sa = fmaf(va[kk], w, sa);
    sb = fmaf(vb[kk], w, sb);
  }
  pd1[(size_t)c * 512 + t] = sa;
  pd1[(size_t)c * 512 + DD + t] = sb;
}

// ---- Kernel 3: attention rows, same structure; reduces pd1 partials ----
__global__ __launch_bounds__(256) void k_att(const float* __restrict__ pd1,
                                             const float* __restrict__ Att,
                                             float* __restrict__ patt) {
  const int c = blockIdx.x;
  const int t = threadIdx.x;
  const int jbase = (c & 7) * 32;
  __shared__ float A[32], B[32], wa[32], wb[32];
  if (t < 64) {
    const int row = t >> 5;
    const int jj = t & 31;
    const int col = row * DD + jbase + jj;
    float s = 0.f;
#pragma unroll
    for (int b = 0; b < 16; ++b) s += pd1[(size_t)b * 512 + col];
    if (row == 0) A[jj] = s; else B[jj] = s;
  }
  __syncthreads();
  if (t < 32) {
    const float da = A[t], db = B[t];
    if (c < 8) { wa[t] = da; wb[t] = db; }
    else {
      wa[t] = (da + db) * (1.0f / (float)(LL - 1));
      wb[t] = db * (1.0f / (float)LL);
    }
  }
  __syncthreads();
  const int k0 = c * 32;
  float ta = 0.f, tb = 0.f;
#pragma unroll 8
  for (int kk = 0; kk < 32; ++kk) {
    const float w = Att[(size_t)(k0 + kk) * DD + t];
    ta = fmaf(wa[kk], w, ta);
    tb = fmaf(wb[kk], w, tb);
  }
  patt[(size_t)c * 512 + t] = ta;
  patt[(size_t)c * 512 + DD + t] = tb;
}

// ---- Kernel 4: out[i] = sum_d s[d] * D2[d][i],
//      s[d] = da*ta + db*tb (weighted[L-2] + weighted[L-1]).
// 250 blocks x 256 threads; block owns 32 float4 i's, 8-way d-interleave with
// LDS reduce. Each out element written exactly once -> no zeroing needed. ----
__global__ __launch_bounds__(256) void k_out(const float* __restrict__ pd1,
                                             const float* __restrict__ patt,
                                             const float* __restrict__ D2,
                                             float* __restrict__ out) {
  const int t = threadIdx.x;
  __shared__ float sv[DD];
  {
    float da = 0.f, db = 0.f, ta = 0.f, tb = 0.f;
#pragma unroll
    for (int b = 0; b < 16; ++b) {
      const float* p1 = pd1 + (size_t)b * 512;
      const float* p2 = patt + (size_t)b * 512;
      da += p1[t]; db += p1[DD + t];
      ta += p2[t]; tb += p2[DD + t];
    }
    sv[t] = fmaf(da, ta, db * tb);
  }
  __syncthreads();
  const int i4 = blockIdx.x * 32 + (t & 31);  // II/4 = 8000 = 250*32, exact
  const int dsub = t >> 5;                    // 0..7
  const float4* __restrict__ D24 = reinterpret_cast<const float4*>(D2);
  float4 a = {0.f, 0.f, 0.f, 0.f};
#pragma unroll 8
  for (int it = 0; it < 32; ++it) {
    const int d = dsub * 32 + it;
    const float4 v = D24[(size_t)d * (II / 4) + i4];
    const float sk = sv[d];
    a.x = fmaf(sk, v.x, a.x); a.y = fmaf(sk, v.y, a.y);
    a.z = fmaf(sk, v.z, a.z); a.w = fmaf(sk, v.w, a.w);
  }
  __shared__ float4 red[8][32];
  red[dsub][t & 31] = a;
  __syncthreads();
  if (t < 32) {
    float4 s = red[0][t];
#pragma unroll
    for (int r = 1; r < 8; ++r) {
      const float4 v = red[r][t];
      s.x += v.x; s.y += v.y; s.z += v.z; s.w += v.w;
    }
    reinterpret_cast<float4*>(out)[blockIdx.x * 32 + t] = s;
  }
}

}  // namespace

extern "C" void kernel_launch(void* const* d_in, const int* in_sizes, int n_in,
                              void* d_out, int out_size, void* d_ws, size_t ws_size,
                              hipStream_t stream) {
  (void)in_sizes; (void)n_in; (void)out_size; (void)ws_size;
  const float* x   = (const float*)d_in[0];  // [L, I]
  const float* DE  = (const float*)d_in[1];  // [I, D]
  const float* PE  = (const float*)d_in[2];  // [L, D]
  const float* D1  = (const float*)d_in[3];  // [2D, D]
  const float* D2  = (const float*)d_in[4];  // [D, I]
  const float* Att = (const float*)d_in[5];  // [2D, D]
  float* out = (float*)d_out;                // [1, I] fp32
  float* ws = (float*)d_ws;

  float* partial = ws;                  // [250][512] posEmbed partials
  float* pd1     = ws + NB * 512;       // [16][512] dense1 partials
  float* patt    = pd1 + 16 * 512;      // [16][512] attention partials

  k_rows  <<<NB, 256, 0, stream>>>(x, DE, partial);
  k_dense1<<<16, 256, 0, stream>>>(partial, PE, D1, pd1);
  k_att   <<<16, 256, 0, stream>>>(pd1, Att, patt);
  k_out   <<<NB, 256, 0, stream>>>(pd1, patt, D2, out);
}